// Round 7
// baseline (3203.327 us; speedup 1.0000x reference)
//
#include <hip/hip_runtime.h>
#include <hip/hip_bf16.h>
#include <cstdint>

#define HIDDEN 1024
#define INPUT  256
#define BATCH  64
#define TSTEPS 512
#define NGCOL  4096      // 4*HIDDEN
#define KTOT   1280      // HIDDEN + INPUT
#define HBUFN  65536     // BATCH*HIDDEN u32 per buffer

typedef __attribute__((ext_vector_type(8))) short bf16x8;
typedef __attribute__((ext_vector_type(4))) float f32x4;
typedef unsigned long long u64;
typedef unsigned int u32;

__device__ inline short f2bs(float f) {
    union { __hip_bfloat16 h; short s; } u;
    u.h = __float2bfloat16(f);
    return u.s;
}
__device__ inline unsigned short f2bu(float f) {
    union { __hip_bfloat16 h; unsigned short s; } u;
    u.h = __float2bfloat16(f);
    return u.s;
}

// ---------------------------------------------------------------------------
// P1: build unified transposed bf16 weights Wt[4096 cols][1280 k]
//     k in [0,1024)    -> W_hh[k][col]
//     k in [1024,1280) -> W_ih[k-1024][col]
__global__ __launch_bounds__(256) void build_wt(
    const float* __restrict__ Whh, const float* __restrict__ Wih,
    __hip_bfloat16* __restrict__ Wt)
{
    int t = blockIdx.x * 256 + threadIdx.x;   // 0 .. 4096*80-1
    int col = t & 4095;
    int k0  = (t >> 12) * 16;                 // 0..1264
    __hip_bfloat16 tmp[16];
    if (k0 < HIDDEN) {
        #pragma unroll
        for (int i = 0; i < 16; ++i)
            tmp[i] = __float2bfloat16(Whh[(size_t)(k0 + i) * NGCOL + col]);
    } else {
        #pragma unroll
        for (int i = 0; i < 16; ++i)
            tmp[i] = __float2bfloat16(Wih[(size_t)(k0 - HIDDEN + i) * NGCOL + col]);
    }
    #pragma unroll
    for (int i = 0; i < 16; ++i)
        Wt[(size_t)col * KTOT + k0 + i] = tmp[i];
}

// ---------------------------------------------------------------------------
// P2: bias = b_ih + b_hh ; zero both epoch-coded h buffers (epoch 0, h=0)
__global__ __launch_bounds__(256) void init_state(
    const float* __restrict__ bih, const float* __restrict__ bhh,
    float* __restrict__ bias, u32* __restrict__ hbuf)
{
    int i = blockIdx.x * 256 + threadIdx.x;   // 131072 threads
    if (i < NGCOL) bias[i] = bih[i] + bhh[i];
    hbuf[i] = 0u;                              // covers both buffers (2*65536)
}

// ---------------------------------------------------------------------------
// Persistent LSTM, fused data+flag exchange (epoch<<16 | bf16 per element).
// Weights pinned in AGPRs (unified RF; MFMA reads B from AGPR directly).
// 256 wgs: bg = wg>>6 (16 batch rows), cg = wg&63 (16 h-cols -> 64 gate cols).
__global__ __launch_bounds__(512, 2) void lstm_persist(
    const __hip_bfloat16* __restrict__ Wt,
    const float* __restrict__ x,
    u32* __restrict__ hbuf,              // [2][64][1024] epoch-coded
    float* __restrict__ hf,
    const float* __restrict__ bias)
{
    __shared__ float pbuf[8][1025];

    const int tid  = threadIdx.x;
    const int wg   = blockIdx.x;
    const int bg   = wg >> 6;         // 0..3
    const int cg   = wg & 63;         // 0..63
    const int wave = tid >> 6;
    const int lane = tid & 63;
    const int l15  = lane & 15;
    const int l4   = lane >> 4;
    const int b0   = bg * 16;
    const int n0   = cg * 16;

    // ---- weight slice: loaded once, pinned into AGPRs for all 512 steps
    const __hip_bfloat16* wrow = Wt + (size_t)(n0 + l15) * KTOT;
    bf16x8 w[5][4];
    #pragma unroll
    for (int c5 = 0; c5 < 5; ++c5) {
        const int kk = (wave + c5 * 8) * 32 + l4 * 8;
        #pragma unroll
        for (int g = 0; g < 4; ++g)
            w[c5][g] = *(const bf16x8*)(wrow + (size_t)g * 1024 * KTOT + kk);
    }
    #pragma unroll
    for (int c5 = 0; c5 < 5; ++c5)
        #pragma unroll
        for (int g = 0; g < 4; ++g)
            asm volatile("" : "+a"(w[c5][g]));   // into AGPR class

    // ---- persistent per-thread state for reducer threads (tid<256)
    const int br = tid >> 4;          // batch row within group
    const int hc = tid & 15;          // h-col within group
    float creg = 0.f;
    float bi = 0.f, bfr = 0.f, bgg = 0.f, bo = 0.f;
    if (tid < 256) {
        bi  = bias[0 * 1024 + n0 + hc];
        bfr = bias[1 * 1024 + n0 + hc];
        bgg = bias[2 * 1024 + n0 + hc];
        bo  = bias[3 * 1024 + n0 + hc];
    }

    const int hoff = (b0 + l15) * HIDDEN + wave * 32 + l4 * 8;   // u32 units, +c5*256
    const float* xrow = x + ((size_t)(b0 + l15) * TSTEPS) * INPUT + wave * 32 + l4 * 8;

    for (int t = 0; t < TSTEPS; ++t) {
        const u32* hb = hbuf + (t & 1) * HBUFN;        // holds epoch t
        u32*       ho = hbuf + ((t + 1) & 1) * HBUFN;  // receives epoch t+1

        // ---- x fragment + x-part MFMAs BEFORE the poll (independent of h)
        bf16x8 afx;
        {
            const float* xf = xrow + (size_t)t * INPUT;
            float4 pa = *(const float4*)(xf);
            float4 pb = *(const float4*)(xf + 4);
            afx[0] = f2bs(pa.x); afx[1] = f2bs(pa.y); afx[2] = f2bs(pa.z); afx[3] = f2bs(pa.w);
            afx[4] = f2bs(pb.x); afx[5] = f2bs(pb.y); afx[6] = f2bs(pb.z); afx[7] = f2bs(pb.w);
        }
        f32x4 a0 = {0.f, 0.f, 0.f, 0.f};
        f32x4 a1 = a0, a2 = a0, a3 = a0;
        a0 = __builtin_amdgcn_mfma_f32_16x16x32_bf16(afx, w[4][0], a0, 0, 0, 0);
        a1 = __builtin_amdgcn_mfma_f32_16x16x32_bf16(afx, w[4][1], a1, 0, 0, 0);
        a2 = __builtin_amdgcn_mfma_f32_16x16x32_bf16(afx, w[4][2], a2, 0, 0, 0);
        a3 = __builtin_amdgcn_mfma_f32_16x16x32_bf16(afx, w[4][3], a3, 0, 0, 0);

        // ---- poll-load: slice is fresh when every embedded epoch == t
        u64 hq[4][4];
        {
            const u64 want = ((u64)(u32)t << 16) | ((u64)(u32)t << 48);
            const u64 mask = 0xFFFF0000FFFF0000ull;
            for (;;) {
                u64 bad = 0;
                #pragma unroll
                for (int c5 = 0; c5 < 4; ++c5) {
                    const u64* hp = (const u64*)(hb + hoff + c5 * 256);
                    #pragma unroll
                    for (int q = 0; q < 4; ++q) {
                        hq[c5][q] = __hip_atomic_load(hp + q, __ATOMIC_RELAXED,
                                                      __HIP_MEMORY_SCOPE_AGENT);
                        bad |= (hq[c5][q] ^ want) & mask;
                    }
                }
                if (__all(bad == 0)) break;
                __builtin_amdgcn_s_sleep(1);
            }
        }
        // ---- repack: u64 (2 epoch-coded u32) -> packed bf16 pair
        bf16x8 afh[4];
        #pragma unroll
        for (int c5 = 0; c5 < 4; ++c5) {
            union { u32 p[4]; bf16x8 v; } u;
            #pragma unroll
            for (int q = 0; q < 4; ++q) {
                const u64 d = hq[c5][q];
                u.p[q] = (u32)(d & 0xFFFFu) | ((u32)(d >> 32) << 16);
            }
            afh[c5] = u.v;
        }

        #pragma unroll
        for (int c5 = 0; c5 < 4; ++c5) {
            a0 = __builtin_amdgcn_mfma_f32_16x16x32_bf16(afh[c5], w[c5][0], a0, 0, 0, 0);
            a1 = __builtin_amdgcn_mfma_f32_16x16x32_bf16(afh[c5], w[c5][1], a1, 0, 0, 0);
            a2 = __builtin_amdgcn_mfma_f32_16x16x32_bf16(afh[c5], w[c5][2], a2, 0, 0, 0);
            a3 = __builtin_amdgcn_mfma_f32_16x16x32_bf16(afh[c5], w[c5][3], a3, 0, 0, 0);
        }

        // ---- keep weights resident in AGPRs across the backedge
        #pragma unroll
        for (int c5 = 0; c5 < 5; ++c5)
            #pragma unroll
            for (int g = 0; g < 4; ++g)
                asm volatile("" : "+a"(w[c5][g]));

        // D layout: row (batch) = l4*4 + r, col (h-col) = l15
        float* pw = &pbuf[wave][0];
        #pragma unroll
        for (int r = 0; r < 4; ++r) {
            const int row = l4 * 4 + r;
            pw[(0 * 16 + row) * 16 + l15] = a0[r];
            pw[(1 * 16 + row) * 16 + l15] = a1[r];
            pw[(2 * 16 + row) * 16 + l15] = a2[r];
            pw[(3 * 16 + row) * 16 + l15] = a3[r];
        }
        __syncthreads();

        if (tid < 256) {
            float gi = bi, gf = bfr, gg = bgg, go = bo;
            #pragma unroll
            for (int w8 = 0; w8 < 8; ++w8) {
                const float* p = &pbuf[w8][0];
                gi += p[(0 * 16 + br) * 16 + hc];
                gf += p[(1 * 16 + br) * 16 + hc];
                gg += p[(2 * 16 + br) * 16 + hc];
                go += p[(3 * 16 + br) * 16 + hc];
            }
            const float i_ = 1.f / (1.f + __expf(-gi));
            const float f_ = 1.f / (1.f + __expf(-gf));
            const float g_ = tanhf(gg);
            const float o_ = 1.f / (1.f + __expf(-go));
            creg = f_ * creg + i_ * g_;
            const float h = o_ * tanhf(creg);
            if (t == TSTEPS - 1) {
                hf[(b0 + br) * HIDDEN + n0 + hc] = h;
            } else {
                // fused data+flag store: epoch t+1 in the high half
                const u32 val = ((u32)(t + 1) << 16) | (u32)f2bu(h);
                __hip_atomic_store(ho + (b0 + br) * HIDDEN + n0 + hc, val,
                                   __ATOMIC_RELAXED, __HIP_MEMORY_SCOPE_AGENT);
            }
        }
        if (t == TSTEPS - 1) break;
        __syncthreads();   // pbuf reads done before next step's writes
    }
}

// ---------------------------------------------------------------------------
// Epilogue: out[64][256] = h_last(fp32) @ W_out + b_out
__global__ __launch_bounds__(256) void out_proj(
    const float* __restrict__ hf, const float* __restrict__ Wout,
    const float* __restrict__ bout, float* __restrict__ out)
{
    const int b  = blockIdx.x;    // 64
    const int oc = threadIdx.x;   // 256
    const float* hb = hf + (size_t)b * HIDDEN;
    float a0 = 0.f, a1 = 0.f, a2 = 0.f, a3 = 0.f;
    for (int k = 0; k < HIDDEN; k += 4) {
        a0 += hb[k + 0] * Wout[(size_t)(k + 0) * 256 + oc];
        a1 += hb[k + 1] * Wout[(size_t)(k + 1) * 256 + oc];
        a2 += hb[k + 2] * Wout[(size_t)(k + 2) * 256 + oc];
        a3 += hb[k + 3] * Wout[(size_t)(k + 3) * 256 + oc];
    }
    out[b * 256 + oc] = (a0 + a1) + (a2 + a3) + bout[oc];
}

// ---------------------------------------------------------------------------
extern "C" void kernel_launch(void* const* d_in, const int* in_sizes, int n_in,
                              void* d_out, int out_size, void* d_ws, size_t ws_size,
                              hipStream_t stream)
{
    const float* x    = (const float*)d_in[0];
    const float* Wih  = (const float*)d_in[1];
    const float* Whh  = (const float*)d_in[2];
    const float* bih  = (const float*)d_in[3];
    const float* bhh  = (const float*)d_in[4];
    const float* Wout = (const float*)d_in[5];
    const float* bout = (const float*)d_in[6];
    float* out = (float*)d_out;

    char* ws = (char*)d_ws;
    size_t off = 0;
    auto alloc = [&](size_t bytes) -> void* {
        void* p = ws + off;
        off = (off + bytes + 255) & ~(size_t)255;
        return p;
    };
    __hip_bfloat16* Wt = (__hip_bfloat16*)alloc((size_t)NGCOL * KTOT * 2); // 10 MB
    u32*   hbuf = (u32*)alloc((size_t)2 * HBUFN * 4);                      // 512 KB
    float* bias = (float*)alloc((size_t)NGCOL * 4);
    float* hf   = (float*)alloc((size_t)BATCH * HIDDEN * 4);

    build_wt<<<1280, 256, 0, stream>>>(Whh, Wih, Wt);
    init_state<<<512, 256, 0, stream>>>(bih, bhh, bias, hbuf);
    lstm_persist<<<256, 512, 0, stream>>>(Wt, x, hbuf, hf, bias);
    out_proj<<<64, 256, 0, stream>>>(hf, Wout, bout, out);
}

// Round 8
// 2881.062 us; speedup vs baseline: 1.1119x; 1.1119x over previous
//
#include <hip/hip_runtime.h>
#include <hip/hip_bf16.h>
#include <cstdint>

#define HIDDEN 1024
#define INPUT  256
#define BATCH  64
#define TSTEPS 512
#define NGCOL  4096      // 4*HIDDEN
#define KTOT   1280      // HIDDEN + INPUT
#define HBUFN  65536     // BATCH*HIDDEN u32 per buffer
#define FSTRIDE 16       // flag padding: 16 u32 = 64 B per wg

typedef __attribute__((ext_vector_type(8))) short bf16x8;
typedef __attribute__((ext_vector_type(4))) float f32x4;
typedef unsigned long long u64;
typedef unsigned int u32;

__device__ inline short f2bs(float f) {
    union { __hip_bfloat16 h; short s; } u;
    u.h = __float2bfloat16(f);
    return u.s;
}
__device__ inline unsigned short f2bu(float f) {
    union { __hip_bfloat16 h; unsigned short s; } u;
    u.h = __float2bfloat16(f);
    return u.s;
}

// ---------------------------------------------------------------------------
// P1: build unified transposed bf16 weights Wt[4096 cols][1280 k]
__global__ __launch_bounds__(256) void build_wt(
    const float* __restrict__ Whh, const float* __restrict__ Wih,
    __hip_bfloat16* __restrict__ Wt)
{
    int t = blockIdx.x * 256 + threadIdx.x;   // 0 .. 4096*80-1
    int col = t & 4095;
    int k0  = (t >> 12) * 16;                 // 0..1264
    __hip_bfloat16 tmp[16];
    if (k0 < HIDDEN) {
        #pragma unroll
        for (int i = 0; i < 16; ++i)
            tmp[i] = __float2bfloat16(Whh[(size_t)(k0 + i) * NGCOL + col]);
    } else {
        #pragma unroll
        for (int i = 0; i < 16; ++i)
            tmp[i] = __float2bfloat16(Wih[(size_t)(k0 - HIDDEN + i) * NGCOL + col]);
    }
    #pragma unroll
    for (int i = 0; i < 16; ++i)
        Wt[(size_t)col * KTOT + k0 + i] = tmp[i];
}

// ---------------------------------------------------------------------------
// P2: bias = b_ih + b_hh ; zero epoch-coded h buffers and per-wg flags
__global__ __launch_bounds__(256) void init_state(
    const float* __restrict__ bih, const float* __restrict__ bhh,
    float* __restrict__ bias, u32* __restrict__ hbuf, u32* __restrict__ cnt)
{
    int i = blockIdx.x * 256 + threadIdx.x;   // 131072 threads
    if (i < NGCOL) bias[i] = bih[i] + bhh[i];
    hbuf[i] = 0u;                              // both buffers (2*65536)
    if (i < 256 * FSTRIDE) cnt[i] = 0u;
}

// ---------------------------------------------------------------------------
// Persistent LSTM. Exchange protocol:
//   data:  u32 = (epoch<<16) | bf16(h), epoch = t+1, sc1 relaxed-agent stores
//   flag:  per-wg u32 (64B padded), stored AFTER the wg's data stores issue
//          (no vmcnt ack -- flag may race ahead; data epoch is the true gate)
//   poll:  wave polls its 8 producers' flags (1 u32/lane), then reads data
//          slice and verifies embedded epochs (rare short retry).
// 256 wgs: bg = wg>>6 (16 batch rows), cg = wg&63 (16 h-cols -> 64 gate cols).
__global__ __launch_bounds__(512, 2) void lstm_persist(
    const __hip_bfloat16* __restrict__ Wt,
    const float* __restrict__ x,
    u32* __restrict__ hbuf,              // [2][64][1024] epoch-coded
    float* __restrict__ hf,
    const float* __restrict__ bias,
    u32* __restrict__ cnt)               // [256][FSTRIDE] flags
{
    __shared__ float pbuf[8][1025];

    const int tid  = threadIdx.x;
    const int wg   = blockIdx.x;
    const int bg   = wg >> 6;         // 0..3
    const int cg   = wg & 63;         // 0..63
    const int wave = tid >> 6;
    const int lane = tid & 63;
    const int l15  = lane & 15;
    const int l4   = lane >> 4;
    const int b0   = bg * 16;
    const int n0   = cg * 16;

    // ---- weight slice (plain cached loads; proven off the critical path)
    const __hip_bfloat16* wrow = Wt + (size_t)(n0 + l15) * KTOT;
    bf16x8 w[5][4];
    #pragma unroll
    for (int c5 = 0; c5 < 5; ++c5) {
        const int kk = (wave + c5 * 8) * 32 + l4 * 8;
        #pragma unroll
        for (int g = 0; g < 4; ++g)
            w[c5][g] = *(const bf16x8*)(wrow + (size_t)g * 1024 * KTOT + kk);
    }

    // ---- persistent per-thread state for reducer threads (tid<256)
    const int br = tid >> 4;          // batch row within group
    const int hc = tid & 15;          // h-col within group
    float creg = 0.f;
    float bi = 0.f, bfr = 0.f, bgg = 0.f, bo = 0.f;
    if (tid < 256) {
        bi  = bias[0 * 1024 + n0 + hc];
        bfr = bias[1 * 1024 + n0 + hc];
        bgg = bias[2 * 1024 + n0 + hc];
        bo  = bias[3 * 1024 + n0 + hc];
    }

    const int hoff = (b0 + l15) * HIDDEN + wave * 32 + l4 * 8;   // u32 units, +c5*256
    const float* xrow = x + ((size_t)(b0 + l15) * TSTEPS) * INPUT + wave * 32 + l4 * 8;

    // this wave's 8 producer wgs: cg = 2*wave + (j&1) + 16*(j>>1), j = lane&7
    const int pj = 2 * wave + (lane & 1) + 16 * ((lane >> 1) & 3);
    const u32* myflag = cnt + (size_t)(bg * 64 + pj) * FSTRIDE;

    for (int t = 0; t < TSTEPS; ++t) {
        const u32* hb = hbuf + (t & 1) * HBUFN;        // holds epoch t
        u32*       ho = hbuf + ((t + 1) & 1) * HBUFN;  // receives epoch t+1

        // ---- x fragment + x-part MFMAs BEFORE the poll (independent of h)
        bf16x8 afx;
        {
            const float* xf = xrow + (size_t)t * INPUT;
            float4 pa = *(const float4*)(xf);
            float4 pb = *(const float4*)(xf + 4);
            afx[0] = f2bs(pa.x); afx[1] = f2bs(pa.y); afx[2] = f2bs(pa.z); afx[3] = f2bs(pa.w);
            afx[4] = f2bs(pb.x); afx[5] = f2bs(pb.y); afx[6] = f2bs(pb.z); afx[7] = f2bs(pb.w);
        }
        f32x4 a0 = {0.f, 0.f, 0.f, 0.f};
        f32x4 a1 = a0, a2 = a0, a3 = a0;
        a0 = __builtin_amdgcn_mfma_f32_16x16x32_bf16(afx, w[4][0], a0, 0, 0, 0);
        a1 = __builtin_amdgcn_mfma_f32_16x16x32_bf16(afx, w[4][1], a1, 0, 0, 0);
        a2 = __builtin_amdgcn_mfma_f32_16x16x32_bf16(afx, w[4][2], a2, 0, 0, 0);
        a3 = __builtin_amdgcn_mfma_f32_16x16x32_bf16(afx, w[4][3], a3, 0, 0, 0);

        // ---- cheap flag pre-filter: 1 u32 per lane, 8 producers per wave
        for (;;) {
            u32 f = __hip_atomic_load(myflag, __ATOMIC_RELAXED, __HIP_MEMORY_SCOPE_AGENT);
            if (__all(f >= (u32)t)) break;
            __builtin_amdgcn_s_sleep(1);
        }

        // ---- data read + epoch verify (true gate; rare short retry)
        u64 hq[4][4];
        {
            const u64 want = ((u64)(u32)t << 16) | ((u64)(u32)t << 48);
            const u64 mask = 0xFFFF0000FFFF0000ull;
            for (;;) {
                u64 bad = 0;
                #pragma unroll
                for (int c5 = 0; c5 < 4; ++c5) {
                    const u64* hp = (const u64*)(hb + hoff + c5 * 256);
                    #pragma unroll
                    for (int q = 0; q < 4; ++q) {
                        hq[c5][q] = __hip_atomic_load(hp + q, __ATOMIC_RELAXED,
                                                      __HIP_MEMORY_SCOPE_AGENT);
                        bad |= (hq[c5][q] ^ want) & mask;
                    }
                }
                if (__all(bad == 0)) break;
                __builtin_amdgcn_s_sleep(1);
            }
        }
        // ---- repack: u64 (2 epoch-coded u32) -> packed bf16 pair
        bf16x8 afh[4];
        #pragma unroll
        for (int c5 = 0; c5 < 4; ++c5) {
            union { u32 p[4]; bf16x8 v; } u;
            #pragma unroll
            for (int q = 0; q < 4; ++q) {
                const u64 d = hq[c5][q];
                u.p[q] = (u32)(d & 0xFFFFu) | ((u32)(d >> 32) << 16);
            }
            afh[c5] = u.v;
        }

        #pragma unroll
        for (int c5 = 0; c5 < 4; ++c5) {
            a0 = __builtin_amdgcn_mfma_f32_16x16x32_bf16(afh[c5], w[c5][0], a0, 0, 0, 0);
            a1 = __builtin_amdgcn_mfma_f32_16x16x32_bf16(afh[c5], w[c5][1], a1, 0, 0, 0);
            a2 = __builtin_amdgcn_mfma_f32_16x16x32_bf16(afh[c5], w[c5][2], a2, 0, 0, 0);
            a3 = __builtin_amdgcn_mfma_f32_16x16x32_bf16(afh[c5], w[c5][3], a3, 0, 0, 0);
        }

        // D layout: row (batch) = l4*4 + r, col (h-col) = l15
        float* pw = &pbuf[wave][0];
        #pragma unroll
        for (int r = 0; r < 4; ++r) {
            const int row = l4 * 4 + r;
            pw[(0 * 16 + row) * 16 + l15] = a0[r];
            pw[(1 * 16 + row) * 16 + l15] = a1[r];
            pw[(2 * 16 + row) * 16 + l15] = a2[r];
            pw[(3 * 16 + row) * 16 + l15] = a3[r];
        }
        __syncthreads();

        if (tid < 256) {
            float gi = bi, gf = bfr, gg = bgg, go = bo;
            #pragma unroll
            for (int w8 = 0; w8 < 8; ++w8) {
                const float* p = &pbuf[w8][0];
                gi += p[(0 * 16 + br) * 16 + hc];
                gf += p[(1 * 16 + br) * 16 + hc];
                gg += p[(2 * 16 + br) * 16 + hc];
                go += p[(3 * 16 + br) * 16 + hc];
            }
            const float i_ = 1.f / (1.f + __expf(-gi));
            const float f_ = 1.f / (1.f + __expf(-gf));
            const float g_ = tanhf(gg);
            const float o_ = 1.f / (1.f + __expf(-go));
            creg = f_ * creg + i_ * g_;
            const float h = o_ * tanhf(creg);
            if (t == TSTEPS - 1) {
                hf[(b0 + br) * HIDDEN + n0 + hc] = h;
            } else {
                const u32 val = ((u32)(t + 1) << 16) | (u32)f2bu(h);
                __hip_atomic_store(ho + (b0 + br) * HIDDEN + n0 + hc, val,
                                   __ATOMIC_RELAXED, __HIP_MEMORY_SCOPE_AGENT);
            }
        }
        if (t == TSTEPS - 1) break;
        __syncthreads();   // all data stores issued; pbuf safe for next step

        if (tid == 0)      // flag may race ahead of data -- epoch verify covers
            __hip_atomic_store(cnt + (size_t)wg * FSTRIDE, (u32)(t + 1),
                               __ATOMIC_RELAXED, __HIP_MEMORY_SCOPE_AGENT);
    }
}

// ---------------------------------------------------------------------------
// Epilogue: out[64][256] = h_last(fp32) @ W_out + b_out
__global__ __launch_bounds__(256) void out_proj(
    const float* __restrict__ hf, const float* __restrict__ Wout,
    const float* __restrict__ bout, float* __restrict__ out)
{
    const int b  = blockIdx.x;    // 64
    const int oc = threadIdx.x;   // 256
    const float* hb = hf + (size_t)b * HIDDEN;
    float a0 = 0.f, a1 = 0.f, a2 = 0.f, a3 = 0.f;
    for (int k = 0; k < HIDDEN; k += 4) {
        a0 += hb[k + 0] * Wout[(size_t)(k + 0) * 256 + oc];
        a1 += hb[k + 1] * Wout[(size_t)(k + 1) * 256 + oc];
        a2 += hb[k + 2] * Wout[(size_t)(k + 2) * 256 + oc];
        a3 += hb[k + 3] * Wout[(size_t)(k + 3) * 256 + oc];
    }
    out[b * 256 + oc] = (a0 + a1) + (a2 + a3) + bout[oc];
}

// ---------------------------------------------------------------------------
extern "C" void kernel_launch(void* const* d_in, const int* in_sizes, int n_in,
                              void* d_out, int out_size, void* d_ws, size_t ws_size,
                              hipStream_t stream)
{
    const float* x    = (const float*)d_in[0];
    const float* Wih  = (const float*)d_in[1];
    const float* Whh  = (const float*)d_in[2];
    const float* bih  = (const float*)d_in[3];
    const float* bhh  = (const float*)d_in[4];
    const float* Wout = (const float*)d_in[5];
    const float* bout = (const float*)d_in[6];
    float* out = (float*)d_out;

    char* ws = (char*)d_ws;
    size_t off = 0;
    auto alloc = [&](size_t bytes) -> void* {
        void* p = ws + off;
        off = (off + bytes + 255) & ~(size_t)255;
        return p;
    };
    __hip_bfloat16* Wt = (__hip_bfloat16*)alloc((size_t)NGCOL * KTOT * 2); // 10 MB
    u32*   hbuf = (u32*)alloc((size_t)2 * HBUFN * 4);                      // 512 KB
    float* bias = (float*)alloc((size_t)NGCOL * 4);
    float* hf   = (float*)alloc((size_t)BATCH * HIDDEN * 4);
    u32*   cnt  = (u32*)alloc((size_t)256 * FSTRIDE * 4);                  // 16 KB

    build_wt<<<1280, 256, 0, stream>>>(Whh, Wih, Wt);
    init_state<<<512, 256, 0, stream>>>(bih, bhh, bias, hbuf, cnt);
    lstm_persist<<<256, 512, 0, stream>>>(Wt, x, hbuf, hf, bias, cnt);
    out_proj<<<64, 256, 0, stream>>>(hf, Wout, bout, out);
}